// Round 19
// baseline (838.544 us; speedup 1.0000x reference)
//
#include <hip/hip_runtime.h>
#include <hip/hip_bf16.h>
#include <hip/hip_fp16.h>
#include <math.h>

#define N_NODES 50000
#define N_EDGES 800000
#define N_GRAPHS 256
#define DIM 64
#define EDIM 50
#define HDIM 128
#define NLAYER 4
#define ZDIM (2 * DIM + EDIM)  // 178
#define NTILES (N_EDGES / 32)  // 25000

typedef _Float16 f16;
typedef __attribute__((ext_vector_type(4))) _Float16 half4v;
typedef __attribute__((ext_vector_type(8))) _Float16 half8v;
typedef __attribute__((ext_vector_type(16))) float f32x16;

__device__ __forceinline__ float softplus_f(float x) {
    return fmaxf(x, 0.0f) + log1pf(__expf(-fabsf(x)));
}

// branchless sigmoid: t=2^(-x/ln2); large -x -> t=inf -> rcp(inf)=0 (correct tail)
__device__ __forceinline__ float sigx(float x) {
    float t = __builtin_amdgcn_exp2f(-1.44269504f * x);
    return __builtin_amdgcn_rcpf(1.0f + t);
}
// STABLE softplus in exp2 domain: exact in the linear tail
__device__ __forceinline__ float spx(float y) {
    float t = __builtin_amdgcn_exp2f(-1.44269504f * fabsf(y));
    return fmaxf(y, 0.0f) + 0.69314718f * __builtin_amdgcn_logf(1.0f + t);
}

// Fused weight prep (fp16): wcat (edge weights) + wnode (node weights).
// wcat[l][k][colv] = (k<50) ? W_g[l][128+k][d] : 0, colv = g*64+d
// wnode[l][colv2][k] = W_g[l][half*64+k][d], colv2 = half*128+g*64+d
__global__ void k_wprep(const float* __restrict__ Wf, const float* __restrict__ Ws,
                        f16* __restrict__ wcat, f16* __restrict__ wnode) {
    int i = blockIdx.x * 256 + threadIdx.x;  // 32768 + 65536 = 98304
    if (i < 32768) {
        int l = i >> 13;
        int rem = i & 8191;
        int k = rem >> 7;
        int colv = rem & 127;
        int g = colv >> 6, d = colv & 63;
        float v = 0.0f;
        if (k < 50) {
            const float* W = g ? Ws : Wf;
            v = W[((size_t)l * ZDIM + 128 + k) * 64 + d];
        }
        wcat[i] = (f16)v;
    } else {
        int j = i - 32768;
        int l = j >> 14;
        int rem = j & 16383;
        int colv2 = rem >> 6;
        int k = rem & 63;
        int half = colv2 >> 7, g = (colv2 >> 6) & 1, d = colv2 & 63;
        const float* W = g ? Ws : Wf;
        wnode[j] = (f16)W[((size_t)l * ZDIM + half * 64 + k) * 64 + d];
    }
}

// ---------------- dst-sort (counting sort) ----------------
__global__ void k_hist(const int* __restrict__ eidx, int* __restrict__ hist) {
    int e = blockIdx.x * 256 + threadIdx.x;  // E exact
    atomicAdd(&hist[eidx[N_EDGES + e]], 1);
}

__global__ __launch_bounds__(256) void k_scan1(const int* __restrict__ hist,
                                               int* __restrict__ scanbuf,
                                               int* __restrict__ blocksums) {
    int tid = threadIdx.x;
    int i = blockIdx.x * 256 + tid;
    int v = (i < N_NODES) ? hist[i] : 0;
    int lane = tid & 63;
#pragma unroll
    for (int off = 1; off < 64; off <<= 1) {
        int u = __shfl_up(v, off);
        if (lane >= off) v += u;
    }
    __shared__ int wsum[4];
    if (lane == 63) wsum[tid >> 6] = v;
    __syncthreads();
    int w = tid >> 6;
    int add = 0;
#pragma unroll
    for (int k = 0; k < 3; ++k)
        if (k < w) add += wsum[k];
    v += add;
    if (i < N_NODES) scanbuf[i] = v;
    if (tid == 255) blocksums[blockIdx.x] = v;
}

__global__ __launch_bounds__(256) void k_scan2(int* __restrict__ blocksums, int nb) {
    int tid = threadIdx.x;
    int v = (tid < nb) ? blocksums[tid] : 0;
    int lane = tid & 63;
#pragma unroll
    for (int off = 1; off < 64; off <<= 1) {
        int u = __shfl_up(v, off);
        if (lane >= off) v += u;
    }
    __shared__ int wsum[4];
    if (lane == 63) wsum[tid >> 6] = v;
    __syncthreads();
    int w = tid >> 6;
    int add = 0;
#pragma unroll
    for (int k = 0; k < 3; ++k)
        if (k < w) add += wsum[k];
    v += add;
    if (tid < nb) blocksums[tid] = v;
}

__global__ void k_scan3(const int* __restrict__ scanbuf, const int* __restrict__ hist,
                        const int* __restrict__ blocksums, int* __restrict__ cursor) {
    int i = blockIdx.x * 256 + threadIdx.x;
    if (i >= N_NODES) return;
    int b = blockIdx.x;
    int off = b ? blocksums[b - 1] : 0;
    cursor[i] = scanbuf[i] - hist[i] + off;
}

__global__ void k_scatter(const int* __restrict__ eidx, int* __restrict__ cursor,
                          int* __restrict__ perm, int* __restrict__ permSrc,
                          int* __restrict__ permDst) {
    int e = blockIdx.x * 256 + threadIdx.x;
    int d = eidx[N_EDGES + e];
    int pos = atomicAdd(&cursor[d], 1);
    perm[pos] = e;
    permDst[pos] = d;
    permSrc[pos] = eidx[e];
}

// Original-order fp16 pack: eattrP[edge][k] = (k<50)? eattr[edge][k] : 0 (k padded 64).
// Fully coalesced read AND write (no perm gather, no scattered stores).
__global__ void k_eprep3(const float* __restrict__ eattr, f16* __restrict__ eattrP) {
    int i = blockIdx.x * 256 + threadIdx.x;  // over E*64 = 51.2M
    int edge = i >> 6, k = i & 63;
    float v = (k < EDIM) ? eattr[(size_t)edge * EDIM + k] : 0.0f;
    eattrP[i] = (f16)v;
}

// MFMA node-side matmuls (f16 inputs): hsf[64][64] @ wnode[64][256] -> fp16 packs.
// Wave w owns colv2 in [64w,64w+64). MODE 1: fused update. MODE 2: fused embed.
template <int MODE>
__global__ __launch_bounds__(256) void k_nodemm(
    const float* __restrict__ hin, float* __restrict__ hout, float* __restrict__ agg,
    const int* __restrict__ x, const float* __restrict__ emb,
    const float* __restrict__ bf, const float* __restrict__ bs,
    const f16* __restrict__ wnode_l,  // [256][64] fp16
    __half* __restrict__ dstpack, __half* __restrict__ srcpack) {
    __shared__ f16 hsf[64 * 68];  // fp16, pitch 68
    int tid = threadIdx.x;
    int w = tid >> 6, lane = tid & 63;
    int c = lane & 31, h2 = lane >> 5;
    int n0 = blockIdx.x * 64;
    for (int idx = tid; idx < 64 * 64; idx += 256) {
        int i = idx >> 6, k = idx & 63;
        int n = n0 + i;
        float v = 0.0f;
        if (n < N_NODES) {
            if (MODE == 1) {
                v = softplus_f(hin[(size_t)n * DIM + k] + agg[(size_t)n * DIM + k]);
                agg[(size_t)n * DIM + k] = 0.0f;
                hout[(size_t)n * DIM + k] = v;
            } else {
                v = emb[x[n] * DIM + k];
                hout[(size_t)n * DIM + k] = v;
            }
        }
        hsf[i * 68 + k] = (f16)v;
    }
    __syncthreads();

    // B fragments from wnode (L2-resident, 16B-aligned)
    half8v bfr[2][4];
#pragma unroll
    for (int nt = 0; nt < 2; ++nt) {
#pragma unroll
        for (int kk = 0; kk < 4; ++kk) {
            bfr[nt][kk] = *(const half8v*)(wnode_l + ((64 * w + 32 * nt + c) * 64 + kk * 16 + 8 * h2));
        }
    }
    float bias[2];
#pragma unroll
    for (int nt = 0; nt < 2; ++nt) {
        int d = 32 * nt + c;
        bias[nt] = (w == 0) ? bf[d] : (w == 1) ? bs[d] : 0.0f;
    }

    f32x16 acc[2][2];
#pragma unroll
    for (int mt = 0; mt < 2; ++mt)
#pragma unroll
        for (int nt = 0; nt < 2; ++nt)
#pragma unroll
            for (int i = 0; i < 16; ++i) acc[mt][nt][i] = 0.0f;

#pragma unroll
    for (int mt = 0; mt < 2; ++mt) {
        half8v afr[4];
#pragma unroll
        for (int kk = 0; kk < 4; ++kk) {
            const f16* ap = &hsf[(32 * mt + c) * 68 + kk * 16 + 8 * h2];
            half8v a;
            *(half4v*)&a = *(const half4v*)ap;            // 8B-aligned LDS reads
            *((half4v*)&a + 1) = *(const half4v*)(ap + 4);
            afr[kk] = a;
        }
#pragma unroll
        for (int nt = 0; nt < 2; ++nt)
#pragma unroll
            for (int kk = 0; kk < 4; ++kk)
                acc[mt][nt] = __builtin_amdgcn_mfma_f32_32x32x16_f16(afr[kk], bfr[nt][kk],
                                                                     acc[mt][nt], 0, 0, 0);
    }

    __half* outp = (w < 2) ? dstpack : srcpack;
    int colbase = (w & 1) * 64;
#pragma unroll
    for (int mt = 0; mt < 2; ++mt) {
#pragma unroll
        for (int nt = 0; nt < 2; ++nt) {
#pragma unroll
            for (int r = 0; r < 16; ++r) {
                int row = 32 * mt + (r & 3) + 8 * (r >> 2) + 4 * h2;
                int n = n0 + row;
                if (n < N_NODES) {
                    outp[(size_t)n * 128 + colbase + 32 * nt + c] =
                        __float2half(acc[mt][nt][r] + bias[nt]);
                }
            }
        }
    }
}

// ---------------- sorted edge kernel (round-16 schedule; eattrP gathered via perm) ----------------
// Transposed MFMA: D[feat][edge], lane owns ONE edge (c = lane&31).
// waves 0,1 -> feats 0..63 (sigmoid); waves 2,3 -> feats 64..127 (softplus).
__global__ __launch_bounds__(256) void k_edge_s(
    const int* __restrict__ perm, const int* __restrict__ permSrc,
    const int* __restrict__ permDst,
    const f16* __restrict__ eattrP, const __half* __restrict__ dstpack,
    const __half* __restrict__ srcpack, const f16* __restrict__ wcat_l,
    float* __restrict__ agg) {
    __shared__ float msgV[2][64][34];  // [gate][d][edge], pitch 34
    __shared__ int dsh[32];
    int tid = threadIdx.x;
    int w = tid >> 6;
    int lane = tid & 63;
    int c = lane & 31;   // edge within tile
    int h2 = lane >> 5;
    int col = w * 32 + c;  // feature colv for the weight A-fragment

    // Weight A-fragments
    half8v wfr[4];
#pragma unroll
    for (int kk = 0; kk < 4; ++kk) {
#pragma unroll
        for (int e = 0; e < 8; ++e) {
            wfr[kk][e] = wcat_l[(kk * 16 + 8 * h2 + e) * 128 + col];
        }
    }

    for (int tile = blockIdx.x; tile < NTILES; tile += gridDim.x) {
        int e0 = tile * 32;
        int tI = permDst[e0 + c];
        int sI = permSrc[e0 + c];
        int pe = perm[e0 + c];
        if (tid < 32) dsh[tid] = tI;  // wave 0: c == tid

        // fragments from original-order pack: 4x16B at pe's 128B row (h2 halves
        // jointly consume the full row -> no over-fetch despite random pe)
        half8v efr[4];
        const f16* ebase = eattrP + ((size_t)(unsigned)pe << 6) + 8 * h2;
#pragma unroll
        for (int kk = 0; kk < 4; ++kk) {
            efr[kk] = *(const half8v*)(ebase + kk * 16);
        }

        f32x16 acc;
#pragma unroll
        for (int i = 0; i < 16; ++i) acc[i] = 0.0f;
#pragma unroll
        for (int kk = 0; kk < 4; ++kk) {
            acc = __builtin_amdgcn_mfma_f32_32x32x16_f16(wfr[kk], efr[kk], acc, 0, 0, 0);
        }

        // fp16 gathers: one row each from dstpack/srcpack, 4x8B per table
        const __half* drow = dstpack + (((size_t)(unsigned)tI) << 7) + w * 32 + 4 * h2;
        const __half* srow = srcpack + (((size_t)(unsigned)sI) << 7) + w * 32 + 4 * h2;
        float dv[4][4], sv[4][4];
#pragma unroll
        for (int q = 0; q < 4; ++q) {
            const __half2* dp = (const __half2*)(drow + 8 * q);
            float2 lo = __half22float2(dp[0]);
            float2 hi = __half22float2(dp[1]);
            dv[q][0] = lo.x; dv[q][1] = lo.y; dv[q][2] = hi.x; dv[q][3] = hi.y;
        }
#pragma unroll
        for (int q = 0; q < 4; ++q) {
            const __half2* sp = (const __half2*)(srow + 8 * q);
            float2 lo = __half22float2(sp[0]);
            float2 hi = __half22float2(sp[1]);
            sv[q][0] = lo.x; sv[q][1] = lo.y; sv[q][2] = hi.x; sv[q][3] = hi.y;
        }

        int dbase = (w & 1) * 32 + 4 * h2;  // d = dbase + 8*q + i
        if (w < 2) {  // sigmoid, gate 0
#pragma unroll
            for (int q = 0; q < 4; ++q) {
#pragma unroll
                for (int i = 0; i < 4; ++i) {
                    float pre = acc[4 * q + i] + dv[q][i] + sv[q][i];
                    msgV[0][dbase + 8 * q + i][c] = sigx(pre);
                }
            }
        } else {  // softplus, gate 1
#pragma unroll
            for (int q = 0; q < 4; ++q) {
#pragma unroll
                for (int i = 0; i < 4; ++i) {
                    float pre = acc[4 * q + i] + dv[q][i] + sv[q][i];
                    msgV[1][dbase + 8 * q + i][c] = spx(pre);
                }
            }
        }

        __syncthreads();

        // paired segmented scan: thread -> (d = tid&63, edges (tid>>6)*8 .. +8)
        {
            int d = tid & 63;
            int base = (tid >> 6) * 8;
            float m[8];
#pragma unroll
            for (int j2 = 0; j2 < 4; ++j2) {
                float2 a = *(const float2*)&msgV[0][d][base + 2 * j2];
                float2 b = *(const float2*)&msgV[1][d][base + 2 * j2];
                m[2 * j2] = a.x * b.x;
                m[2 * j2 + 1] = a.y * b.y;
            }
            float accum = 0.0f;
            int cur = dsh[base];
#pragma unroll
            for (int j = 0; j < 8; ++j) {
                int dn = dsh[base + j];
                if (dn != cur) {
                    unsafeAtomicAdd(&agg[(unsigned)((cur << 6) + d)], accum);
                    accum = 0.0f;
                    cur = dn;
                }
                accum += m[j];
            }
            unsafeAtomicAdd(&agg[(unsigned)((cur << 6) + d)], accum);
        }
        __syncthreads();
    }
}

// Unsorted fallback (only if ws too small for sort buffers).
__global__ __launch_bounds__(256) void k_edge_u(
    const int* __restrict__ eidx, const float* __restrict__ eattr,
    const __half* __restrict__ dstpack, const __half* __restrict__ srcpack,
    const f16* __restrict__ wcat_l, float* __restrict__ agg) {
    __shared__ float msgV[2][32][64];
    __shared__ int dsh[32], ssh[32];
    int tid = threadIdx.x;
    int w = tid >> 6;
    int lane = tid & 63;
    int c = lane & 31;
    int h2 = lane >> 5;
    int col = w * 32 + c;
    int dcol = (w & 1) * 32 + c;

    half8v bfr[4];
#pragma unroll
    for (int kk = 0; kk < 4; ++kk) {
#pragma unroll
        for (int e = 0; e < 8; ++e) bfr[kk][e] = wcat_l[(kk * 16 + 8 * h2 + e) * 128 + col];
    }

    for (int tile = blockIdx.x; tile < NTILES; tile += gridDim.x) {
        int e0 = tile * 32;
        if (lane < 32) {
            dsh[lane] = eidx[N_EDGES + e0 + lane];
            ssh[lane] = eidx[e0 + lane];
        }
        half8v afr[4];
        const float* erow = eattr + (size_t)(e0 + c) * EDIM;
#pragma unroll
        for (int kk = 0; kk < 3; ++kk) {
            int k0 = kk * 16 + 8 * h2;
#pragma unroll
            for (int p = 0; p < 4; ++p) {
                float2 v = *(const float2*)(erow + k0 + 2 * p);
                afr[kk][2 * p] = (f16)v.x;
                afr[kk][2 * p + 1] = (f16)v.y;
            }
        }
        {
            half8v a;
#pragma unroll
            for (int e = 0; e < 8; ++e) a[e] = (f16)0.0f;
            if (h2 == 0) {
                float2 v = *(const float2*)(erow + 48);
                a[0] = (f16)v.x;
                a[1] = (f16)v.y;
            }
            afr[3] = a;
        }
        f32x16 acc;
#pragma unroll
        for (int i = 0; i < 16; ++i) acc[i] = 0.0f;
#pragma unroll
        for (int kk = 0; kk < 4; ++kk)
            acc = __builtin_amdgcn_mfma_f32_32x32x16_f16(afr[kk], bfr[kk], acc, 0, 0, 0);

        __builtin_amdgcn_wave_barrier();

#pragma unroll
        for (int grp = 0; grp < 2; ++grp) {
            int tI[8], sI[8];
            float dv[8], sv[8];
#pragma unroll
            for (int r = 0; r < 8; ++r) {
                int rr = grp * 8 + r;
                int row = (rr & 3) + 8 * (rr >> 2) + 4 * h2;
                tI[r] = dsh[row];
                sI[r] = ssh[row];
            }
#pragma unroll
            for (int r = 0; r < 8; ++r) {
                dv[r] = __half2float(dstpack[(unsigned)((tI[r] << 7) + col)]);
                sv[r] = __half2float(srcpack[(unsigned)((sI[r] << 7) + col)]);
            }
            float pre[8];
#pragma unroll
            for (int r = 0; r < 8; ++r) pre[r] = acc[grp * 8 + r] + dv[r] + sv[r];
            if (w < 2) {
#pragma unroll
                for (int r = 0; r < 8; ++r) {
                    int rr = grp * 8 + r;
                    int row = (rr & 3) + 8 * (rr >> 2) + 4 * h2;
                    msgV[0][row][dcol] = sigx(pre[r]);
                }
            } else {
#pragma unroll
                for (int r = 0; r < 8; ++r) {
                    int rr = grp * 8 + r;
                    int row = (rr & 3) + 8 * (rr >> 2) + 4 * h2;
                    msgV[1][row][dcol] = spx(pre[r]);
                }
            }
        }
        __syncthreads();
        {
            int d = tid & 63;
            int base = (tid >> 6) * 8;
#pragma unroll
            for (int j = 0; j < 8; ++j) {
                int row = base + j;
                float m = msgV[0][row][d] * msgV[1][row][d];
                unsafeAtomicAdd(&agg[(unsigned)((dsh[row] << 6) + d)], m);
            }
        }
        __syncthreads();
    }
}

// Fused final update + sorted-batch pool: val = softplus(h+agg), run-length
// accumulate, one atomic per graph transition. agg left dirty (re-memset next call).
__global__ __launch_bounds__(256) void k_pool_s(
    const float* __restrict__ h, const float* __restrict__ agg,
    const int* __restrict__ batch,
    float* __restrict__ pooled, float* __restrict__ counts) {
    int tid = threadIdx.x;
    int d = tid & 63;
    int strm = tid >> 6;
    int base = blockIdx.x * 256 + strm * 64;
    if (base >= N_NODES) return;
    int end = min(base + 64, N_NODES);
    float accum = 0.0f;
    int cnt = 0;
    int cur = batch[base];
    for (int n = base; n < end; ++n) {
        int g = batch[n];
        if (g != cur) {
            unsafeAtomicAdd(&pooled[cur * DIM + d], accum);
            if (d == 0) unsafeAtomicAdd(&counts[cur], (float)cnt);
            accum = 0.0f;
            cnt = 0;
            cur = g;
        }
        accum += softplus_f(h[(size_t)n * DIM + d] + agg[(size_t)n * DIM + d]);
        cnt++;
    }
    unsafeAtomicAdd(&pooled[cur * DIM + d], accum);
    if (d == 0) unsafeAtomicAdd(&counts[cur], (float)cnt);
}

__global__ __launch_bounds__(64) void k_mlp(
    const float* __restrict__ pooled, const float* __restrict__ counts,
    const float* __restrict__ W1, const float* __restrict__ b1,
    const float* __restrict__ W2, const float* __restrict__ b2,
    const float* __restrict__ Wo, const float* __restrict__ bo,
    float* __restrict__ out) {
    __shared__ float ps[64];
    __shared__ float h1[128];
    int g = blockIdx.x, lane = threadIdx.x;
    float cnt = fmaxf(counts[g], 1.0f);
    ps[lane] = pooled[g * DIM + lane] / cnt;
    __syncthreads();
#pragma unroll
    for (int rep = 0; rep < 2; ++rep) {
        int j = lane + rep * 64;
        float acc = b1[j];
        for (int k = 0; k < 64; ++k) acc += ps[k] * W1[k * HDIM + j];
        h1[j] = fmaxf(acc, 0.0f);
    }
    __syncthreads();
    float acc = b2[lane];
    for (int k = 0; k < 128; ++k) acc += h1[k] * W2[k * 64 + lane];
    float v = fmaxf(acc, 0.0f) * Wo[lane];
#pragma unroll
    for (int off = 32; off; off >>= 1) v += __shfl_down(v, off);
    if (lane == 0) out[g] = v + bo[0];
}

extern "C" void kernel_launch(void* const* d_in, const int* in_sizes, int n_in,
                              void* d_out, int out_size, void* d_ws, size_t ws_size,
                              hipStream_t stream) {
    const int* x = (const int*)d_in[0];
    const int* eidx = (const int*)d_in[1];
    const float* eattr = (const float*)d_in[2];
    const int* batch = (const int*)d_in[3];
    const float* emb = (const float*)d_in[4];
    const float* Wf = (const float*)d_in[5];
    const float* bf = (const float*)d_in[6];
    const float* Ws = (const float*)d_in[7];
    const float* bs = (const float*)d_in[8];
    const float* W1 = (const float*)d_in[9];
    const float* b1 = (const float*)d_in[10];
    const float* W2 = (const float*)d_in[11];
    const float* b2 = (const float*)d_in[12];
    const float* Wo = (const float*)d_in[13];
    const float* bo = (const float*)d_in[14];
    float* out = (float*)d_out;

    char* p = (char*)d_ws;
    float* h = (float*)p;        p += (size_t)N_NODES * DIM * 4;
    __half* dstpack = (__half*)p; p += (size_t)N_NODES * 2 * DIM * 2;
    __half* srcpack = (__half*)p; p += (size_t)N_NODES * 2 * DIM * 2;
    float* agg = (float*)p;      p += (size_t)N_NODES * DIM * 4;
    float* pooled = (float*)p;   p += (size_t)N_GRAPHS * DIM * 4;
    float* counts = (float*)p;   p += (size_t)N_GRAPHS * 4;
    f16* wcat = (f16*)p;         p += (size_t)NLAYER * 64 * 128 * 2;
    f16* wnode = (f16*)p;        p += (size_t)NLAYER * 256 * 64 * 2;
    f16* eattrP = (f16*)p;       p += (size_t)N_EDGES * 64 * 2;  // 102.4 MB
    int* hist = (int*)p;         p += (size_t)N_NODES * 4;
    int* scanbuf = (int*)p;      p += (size_t)N_NODES * 4;
    int* blocksums = (int*)p;    p += 256 * 4;
    int* cursor = (int*)p;       p += (size_t)N_NODES * 4;
    int* perm = (int*)p;         p += (size_t)N_EDGES * 4;
    int* permSrc = (int*)p;      p += (size_t)N_EDGES * 4;
    int* permDst = (int*)p;      p += (size_t)N_EDGES * 4;
    size_t used_sorted = (size_t)(p - (char*)d_ws);

    bool sorted = used_sorted <= ws_size;

    const int SCAN_BLOCKS = (N_NODES + 255) / 256;  // 196
    const int NODEMM_BLOCKS = (N_NODES + 63) / 64;  // 782

    k_wprep<<<(32768 + 65536) / 256, 256, 0, stream>>>(Wf, Ws, wcat, wnode);
    if (sorted) {
        hipMemsetAsync(hist, 0, (size_t)N_NODES * 4, stream);
        k_hist<<<N_EDGES / 256, 256, 0, stream>>>(eidx, hist);
        k_scan1<<<SCAN_BLOCKS, 256, 0, stream>>>(hist, scanbuf, blocksums);
        k_scan2<<<1, 256, 0, stream>>>(blocksums, SCAN_BLOCKS);
        k_scan3<<<SCAN_BLOCKS, 256, 0, stream>>>(scanbuf, hist, blocksums, cursor);
        k_scatter<<<N_EDGES / 256, 256, 0, stream>>>(eidx, cursor, perm, permSrc, permDst);
        k_eprep3<<<(N_EDGES * 64) / 256, 256, 0, stream>>>(eattr, eattrP);
    }
    // zero agg + pooled + counts in one shot (contiguous in the layout above)
    hipMemsetAsync(agg, 0,
                   (size_t)N_NODES * DIM * 4 + (size_t)N_GRAPHS * DIM * 4 + N_GRAPHS * 4,
                   stream);
    for (int l = 0; l < NLAYER; ++l) {
        const f16* wnl = wnode + (size_t)l * 256 * 64;
        if (l == 0) {
            k_nodemm<2><<<NODEMM_BLOCKS, 256, 0, stream>>>(
                nullptr, h, nullptr, x, emb, bf + l * DIM, bs + l * DIM, wnl,
                dstpack, srcpack);
        } else {
            k_nodemm<1><<<NODEMM_BLOCKS, 256, 0, stream>>>(
                h, h, agg, nullptr, nullptr, bf + l * DIM, bs + l * DIM, wnl,
                dstpack, srcpack);
        }
        if (sorted) {
            k_edge_s<<<2048, 256, 0, stream>>>(perm, permSrc, permDst, eattrP,
                                               dstpack, srcpack,
                                               wcat + (size_t)l * 64 * 128, agg);
        } else {
            k_edge_u<<<2048, 256, 0, stream>>>(eidx, eattr, dstpack, srcpack,
                                               wcat + (size_t)l * 64 * 128, agg);
        }
    }
    k_pool_s<<<(N_NODES + 255) / 256, 256, 0, stream>>>(h, agg, batch, pooled, counts);
    k_mlp<<<N_GRAPHS, 64, 0, stream>>>(pooled, counts, W1, b1, W2, b2, Wo, bo, out);
}

// Round 20
// 675.635 us; speedup vs baseline: 1.2411x; 1.2411x over previous
//
#include <hip/hip_runtime.h>
#include <hip/hip_bf16.h>
#include <hip/hip_fp16.h>
#include <math.h>

#define N_NODES 50000
#define N_EDGES 800000
#define N_GRAPHS 256
#define DIM 64
#define EDIM 50
#define HDIM 128
#define NLAYER 4
#define ZDIM (2 * DIM + EDIM)  // 178
#define NTILES (N_EDGES / 32)  // 25000

typedef _Float16 f16;
typedef __attribute__((ext_vector_type(4))) _Float16 half4v;
typedef __attribute__((ext_vector_type(8))) _Float16 half8v;
typedef __attribute__((ext_vector_type(16))) float f32x16;

__device__ __forceinline__ float softplus_f(float x) {
    return fmaxf(x, 0.0f) + log1pf(__expf(-fabsf(x)));
}

// branchless sigmoid: t=2^(-x/ln2); large -x -> t=inf -> rcp(inf)=0 (correct tail)
__device__ __forceinline__ float sigx(float x) {
    float t = __builtin_amdgcn_exp2f(-1.44269504f * x);
    return __builtin_amdgcn_rcpf(1.0f + t);
}
// STABLE softplus in exp2 domain: exact in the linear tail
__device__ __forceinline__ float spx(float y) {
    float t = __builtin_amdgcn_exp2f(-1.44269504f * fabsf(y));
    return fmaxf(y, 0.0f) + 0.69314718f * __builtin_amdgcn_logf(1.0f + t);
}

// Fused weight prep (fp16): wcat (edge weights) + wnode (node weights).
// wcat[l][k][colv] = (k<50) ? W_g[l][128+k][d] : 0, colv = g*64+d
// wnode[l][colv2][k] = W_g[l][half*64+k][d], colv2 = half*128+g*64+d
__global__ void k_wprep(const float* __restrict__ Wf, const float* __restrict__ Ws,
                        f16* __restrict__ wcat, f16* __restrict__ wnode) {
    int i = blockIdx.x * 256 + threadIdx.x;  // 32768 + 65536 = 98304
    if (i < 32768) {
        int l = i >> 13;
        int rem = i & 8191;
        int k = rem >> 7;
        int colv = rem & 127;
        int g = colv >> 6, d = colv & 63;
        float v = 0.0f;
        if (k < 50) {
            const float* W = g ? Ws : Wf;
            v = W[((size_t)l * ZDIM + 128 + k) * 64 + d];
        }
        wcat[i] = (f16)v;
    } else {
        int j = i - 32768;
        int l = j >> 14;
        int rem = j & 16383;
        int colv2 = rem >> 6;
        int k = rem & 63;
        int half = colv2 >> 7, g = (colv2 >> 6) & 1, d = colv2 & 63;
        const float* W = g ? Ws : Wf;
        wnode[j] = (f16)W[((size_t)l * ZDIM + half * 64 + k) * 64 + d];
    }
}

// ---------------- dst-sort (counting sort) ----------------
__global__ void k_hist(const int* __restrict__ eidx, int* __restrict__ hist) {
    int e = blockIdx.x * 256 + threadIdx.x;  // E exact
    atomicAdd(&hist[eidx[N_EDGES + e]], 1);
}

__global__ __launch_bounds__(256) void k_scan1(const int* __restrict__ hist,
                                               int* __restrict__ scanbuf,
                                               int* __restrict__ blocksums) {
    int tid = threadIdx.x;
    int i = blockIdx.x * 256 + tid;
    int v = (i < N_NODES) ? hist[i] : 0;
    int lane = tid & 63;
#pragma unroll
    for (int off = 1; off < 64; off <<= 1) {
        int u = __shfl_up(v, off);
        if (lane >= off) v += u;
    }
    __shared__ int wsum[4];
    if (lane == 63) wsum[tid >> 6] = v;
    __syncthreads();
    int w = tid >> 6;
    int add = 0;
#pragma unroll
    for (int k = 0; k < 3; ++k)
        if (k < w) add += wsum[k];
    v += add;
    if (i < N_NODES) scanbuf[i] = v;
    if (tid == 255) blocksums[blockIdx.x] = v;
}

__global__ __launch_bounds__(256) void k_scan2(int* __restrict__ blocksums, int nb) {
    int tid = threadIdx.x;
    int v = (tid < nb) ? blocksums[tid] : 0;
    int lane = tid & 63;
#pragma unroll
    for (int off = 1; off < 64; off <<= 1) {
        int u = __shfl_up(v, off);
        if (lane >= off) v += u;
    }
    __shared__ int wsum[4];
    if (lane == 63) wsum[tid >> 6] = v;
    __syncthreads();
    int w = tid >> 6;
    int add = 0;
#pragma unroll
    for (int k = 0; k < 3; ++k)
        if (k < w) add += wsum[k];
    v += add;
    if (tid < nb) blocksums[tid] = v;
}

__global__ void k_scan3(const int* __restrict__ scanbuf, const int* __restrict__ hist,
                        const int* __restrict__ blocksums, int* __restrict__ cursor) {
    int i = blockIdx.x * 256 + threadIdx.x;
    if (i >= N_NODES) return;
    int b = blockIdx.x;
    int off = b ? blocksums[b - 1] : 0;
    cursor[i] = scanbuf[i] - hist[i] + off;
}

__global__ void k_scatter(const int* __restrict__ eidx, int* __restrict__ cursor,
                          int* __restrict__ perm, int* __restrict__ permSrc,
                          int* __restrict__ permDst) {
    int e = blockIdx.x * 256 + threadIdx.x;
    int d = eidx[N_EDGES + e];
    int pos = atomicAdd(&cursor[d], 1);
    perm[pos] = e;
    permDst[pos] = d;
    permSrc[pos] = eidx[e];
}

// Sorted pack (fp16): thread = (tile, lane); handles all 4 kk fragments.
// Random perm-gather reads (latency hidden by high TLP), coalesced writes.
__global__ __launch_bounds__(256) void k_eprep2(const float* __restrict__ eattr,
                                                const int* __restrict__ perm,
                                                f16* __restrict__ eattrP) {
    int i = blockIdx.x * 256 + threadIdx.x;  // over NTILES*64 = 1.6M
    int lane = i & 63;
    int tile = i >> 6;
    int pos = tile * 32 + (lane & 31);
    int h2 = lane >> 5;
    int edge = perm[pos];
    const float* erow = eattr + (size_t)edge * EDIM;  // 8B-aligned (200*edge)
    int k0 = 8 * h2;
    float2 v[12];
#pragma unroll
    for (int kk = 0; kk < 3; ++kk) {
#pragma unroll
        for (int p = 0; p < 4; ++p) {
            v[kk * 4 + p] = *(const float2*)(erow + k0 + 16 * kk + 2 * p);
        }
    }
    float2 t48 = make_float2(0.0f, 0.0f);
    if (h2 == 0) t48 = *(const float2*)(erow + 48);

    unsigned fb = ((unsigned)tile * 4u) * 64u + (unsigned)lane;
#pragma unroll
    for (int kk = 0; kk < 3; ++kk) {
        half8v o;
#pragma unroll
        for (int p = 0; p < 4; ++p) {
            o[2 * p] = (f16)v[kk * 4 + p].x;
            o[2 * p + 1] = (f16)v[kk * 4 + p].y;
        }
        *(half8v*)&eattrP[(fb + (unsigned)kk * 64u) * 8u] = o;
    }
    half8v o;
#pragma unroll
    for (int e = 0; e < 8; ++e) o[e] = (f16)0.0f;
    o[0] = (f16)t48.x;
    o[1] = (f16)t48.y;
    *(half8v*)&eattrP[(fb + 192u) * 8u] = o;
}

// MFMA node-side matmuls (f16 inputs): hsf[64][64] @ wnode[64][256] -> fp16 packs.
// Wave w owns colv2 in [64w,64w+64). MODE 1: fused update. MODE 2: fused embed.
template <int MODE>
__global__ __launch_bounds__(256) void k_nodemm(
    const float* __restrict__ hin, float* __restrict__ hout, float* __restrict__ agg,
    const int* __restrict__ x, const float* __restrict__ emb,
    const float* __restrict__ bf, const float* __restrict__ bs,
    const f16* __restrict__ wnode_l,  // [256][64] fp16
    __half* __restrict__ dstpack, __half* __restrict__ srcpack) {
    __shared__ f16 hsf[64 * 68];  // fp16, pitch 68
    int tid = threadIdx.x;
    int w = tid >> 6, lane = tid & 63;
    int c = lane & 31, h2 = lane >> 5;
    int n0 = blockIdx.x * 64;
    for (int idx = tid; idx < 64 * 64; idx += 256) {
        int i = idx >> 6, k = idx & 63;
        int n = n0 + i;
        float v = 0.0f;
        if (n < N_NODES) {
            if (MODE == 1) {
                v = softplus_f(hin[(size_t)n * DIM + k] + agg[(size_t)n * DIM + k]);
                agg[(size_t)n * DIM + k] = 0.0f;
                hout[(size_t)n * DIM + k] = v;
            } else {
                v = emb[x[n] * DIM + k];
                hout[(size_t)n * DIM + k] = v;
            }
        }
        hsf[i * 68 + k] = (f16)v;
    }
    __syncthreads();

    // B fragments from wnode (L2-resident, 16B-aligned)
    half8v bfr[2][4];
#pragma unroll
    for (int nt = 0; nt < 2; ++nt) {
#pragma unroll
        for (int kk = 0; kk < 4; ++kk) {
            bfr[nt][kk] = *(const half8v*)(wnode_l + ((64 * w + 32 * nt + c) * 64 + kk * 16 + 8 * h2));
        }
    }
    float bias[2];
#pragma unroll
    for (int nt = 0; nt < 2; ++nt) {
        int d = 32 * nt + c;
        bias[nt] = (w == 0) ? bf[d] : (w == 1) ? bs[d] : 0.0f;
    }

    f32x16 acc[2][2];
#pragma unroll
    for (int mt = 0; mt < 2; ++mt)
#pragma unroll
        for (int nt = 0; nt < 2; ++nt)
#pragma unroll
            for (int i = 0; i < 16; ++i) acc[mt][nt][i] = 0.0f;

#pragma unroll
    for (int mt = 0; mt < 2; ++mt) {
        half8v afr[4];
#pragma unroll
        for (int kk = 0; kk < 4; ++kk) {
            const f16* ap = &hsf[(32 * mt + c) * 68 + kk * 16 + 8 * h2];
            half8v a;
            *(half4v*)&a = *(const half4v*)ap;            // 8B-aligned LDS reads
            *((half4v*)&a + 1) = *(const half4v*)(ap + 4);
            afr[kk] = a;
        }
#pragma unroll
        for (int nt = 0; nt < 2; ++nt)
#pragma unroll
            for (int kk = 0; kk < 4; ++kk)
                acc[mt][nt] = __builtin_amdgcn_mfma_f32_32x32x16_f16(afr[kk], bfr[nt][kk],
                                                                     acc[mt][nt], 0, 0, 0);
    }

    __half* outp = (w < 2) ? dstpack : srcpack;
    int colbase = (w & 1) * 64;
#pragma unroll
    for (int mt = 0; mt < 2; ++mt) {
#pragma unroll
        for (int nt = 0; nt < 2; ++nt) {
#pragma unroll
            for (int r = 0; r < 16; ++r) {
                int row = 32 * mt + (r & 3) + 8 * (r >> 2) + 4 * h2;
                int n = n0 + row;
                if (n < N_NODES) {
                    outp[(size_t)n * 128 + colbase + 32 * nt + c] =
                        __float2half(acc[mt][nt][r] + bias[nt]);
                }
            }
        }
    }
}

// ---------------- sorted edge kernel (round-16 form: proven 103 us/layer) ----------------
// Transposed MFMA: D[feat][edge], lane owns ONE edge (c = lane&31).
// waves 0,1 -> feats 0..63 (sigmoid); waves 2,3 -> feats 64..127 (softplus).
__global__ __launch_bounds__(256) void k_edge_s(
    const int* __restrict__ permSrc, const int* __restrict__ permDst,
    const f16* __restrict__ eattrP, const __half* __restrict__ dstpack,
    const __half* __restrict__ srcpack, const f16* __restrict__ wcat_l,
    float* __restrict__ agg) {
    __shared__ float msgV[2][64][34];  // [gate][d][edge], pitch 34
    __shared__ int dsh[32];
    int tid = threadIdx.x;
    int w = tid >> 6;
    int lane = tid & 63;
    int c = lane & 31;   // edge within tile
    int h2 = lane >> 5;
    int col = w * 32 + c;  // feature colv for the weight A-fragment

    // Weight A-fragments
    half8v wfr[4];
#pragma unroll
    for (int kk = 0; kk < 4; ++kk) {
#pragma unroll
        for (int e = 0; e < 8; ++e) {
            wfr[kk][e] = wcat_l[(kk * 16 + 8 * h2 + e) * 128 + col];
        }
    }

    for (int tile = blockIdx.x; tile < NTILES; tile += gridDim.x) {
        int e0 = tile * 32;
        int tI = permDst[e0 + c];
        int sI = permSrc[e0 + c];
        if (tid < 32) dsh[tid] = tI;  // wave 0: c == tid

        half8v efr[4];
        unsigned fb = ((unsigned)tile * 4u) * 64u + (unsigned)lane;
#pragma unroll
        for (int kk = 0; kk < 4; ++kk) {
            efr[kk] = *(const half8v*)&eattrP[(fb + (unsigned)kk * 64u) * 8u];
        }

        f32x16 acc;
#pragma unroll
        for (int i = 0; i < 16; ++i) acc[i] = 0.0f;
#pragma unroll
        for (int kk = 0; kk < 4; ++kk) {
            acc = __builtin_amdgcn_mfma_f32_32x32x16_f16(wfr[kk], efr[kk], acc, 0, 0, 0);
        }

        // fp16 gathers: one row each from dstpack/srcpack, 4x8B per table
        const __half* drow = dstpack + (((size_t)(unsigned)tI) << 7) + w * 32 + 4 * h2;
        const __half* srow = srcpack + (((size_t)(unsigned)sI) << 7) + w * 32 + 4 * h2;
        float dv[4][4], sv[4][4];
#pragma unroll
        for (int q = 0; q < 4; ++q) {
            const __half2* dp = (const __half2*)(drow + 8 * q);
            float2 lo = __half22float2(dp[0]);
            float2 hi = __half22float2(dp[1]);
            dv[q][0] = lo.x; dv[q][1] = lo.y; dv[q][2] = hi.x; dv[q][3] = hi.y;
        }
#pragma unroll
        for (int q = 0; q < 4; ++q) {
            const __half2* sp = (const __half2*)(srow + 8 * q);
            float2 lo = __half22float2(sp[0]);
            float2 hi = __half22float2(sp[1]);
            sv[q][0] = lo.x; sv[q][1] = lo.y; sv[q][2] = hi.x; sv[q][3] = hi.y;
        }

        int dbase = (w & 1) * 32 + 4 * h2;  // d = dbase + 8*q + i
        if (w < 2) {  // sigmoid, gate 0
#pragma unroll
            for (int q = 0; q < 4; ++q) {
#pragma unroll
                for (int i = 0; i < 4; ++i) {
                    float pre = acc[4 * q + i] + dv[q][i] + sv[q][i];
                    msgV[0][dbase + 8 * q + i][c] = sigx(pre);
                }
            }
        } else {  // softplus, gate 1
#pragma unroll
            for (int q = 0; q < 4; ++q) {
#pragma unroll
                for (int i = 0; i < 4; ++i) {
                    float pre = acc[4 * q + i] + dv[q][i] + sv[q][i];
                    msgV[1][dbase + 8 * q + i][c] = spx(pre);
                }
            }
        }

        __syncthreads();

        // paired segmented scan: thread -> (d = tid&63, edges (tid>>6)*8 .. +8)
        {
            int d = tid & 63;
            int base = (tid >> 6) * 8;
            float m[8];
#pragma unroll
            for (int j2 = 0; j2 < 4; ++j2) {
                float2 a = *(const float2*)&msgV[0][d][base + 2 * j2];
                float2 b = *(const float2*)&msgV[1][d][base + 2 * j2];
                m[2 * j2] = a.x * b.x;
                m[2 * j2 + 1] = a.y * b.y;
            }
            float accum = 0.0f;
            int cur = dsh[base];
#pragma unroll
            for (int j = 0; j < 8; ++j) {
                int dn = dsh[base + j];
                if (dn != cur) {
                    unsafeAtomicAdd(&agg[(unsigned)((cur << 6) + d)], accum);
                    accum = 0.0f;
                    cur = dn;
                }
                accum += m[j];
            }
            unsafeAtomicAdd(&agg[(unsigned)((cur << 6) + d)], accum);
        }
        __syncthreads();
    }
}

// Unsorted fallback (only if ws too small for sort buffers).
__global__ __launch_bounds__(256) void k_edge_u(
    const int* __restrict__ eidx, const float* __restrict__ eattr,
    const __half* __restrict__ dstpack, const __half* __restrict__ srcpack,
    const f16* __restrict__ wcat_l, float* __restrict__ agg) {
    __shared__ float msgV[2][32][64];
    __shared__ int dsh[32], ssh[32];
    int tid = threadIdx.x;
    int w = tid >> 6;
    int lane = tid & 63;
    int c = lane & 31;
    int h2 = lane >> 5;
    int col = w * 32 + c;
    int dcol = (w & 1) * 32 + c;

    half8v bfr[4];
#pragma unroll
    for (int kk = 0; kk < 4; ++kk) {
#pragma unroll
        for (int e = 0; e < 8; ++e) bfr[kk][e] = wcat_l[(kk * 16 + 8 * h2 + e) * 128 + col];
    }

    for (int tile = blockIdx.x; tile < NTILES; tile += gridDim.x) {
        int e0 = tile * 32;
        if (lane < 32) {
            dsh[lane] = eidx[N_EDGES + e0 + lane];
            ssh[lane] = eidx[e0 + lane];
        }
        half8v afr[4];
        const float* erow = eattr + (size_t)(e0 + c) * EDIM;
#pragma unroll
        for (int kk = 0; kk < 3; ++kk) {
            int k0 = kk * 16 + 8 * h2;
#pragma unroll
            for (int p = 0; p < 4; ++p) {
                float2 v = *(const float2*)(erow + k0 + 2 * p);
                afr[kk][2 * p] = (f16)v.x;
                afr[kk][2 * p + 1] = (f16)v.y;
            }
        }
        {
            half8v a;
#pragma unroll
            for (int e = 0; e < 8; ++e) a[e] = (f16)0.0f;
            if (h2 == 0) {
                float2 v = *(const float2*)(erow + 48);
                a[0] = (f16)v.x;
                a[1] = (f16)v.y;
            }
            afr[3] = a;
        }
        f32x16 acc;
#pragma unroll
        for (int i = 0; i < 16; ++i) acc[i] = 0.0f;
#pragma unroll
        for (int kk = 0; kk < 4; ++kk)
            acc = __builtin_amdgcn_mfma_f32_32x32x16_f16(afr[kk], bfr[kk], acc, 0, 0, 0);

        __builtin_amdgcn_wave_barrier();

#pragma unroll
        for (int grp = 0; grp < 2; ++grp) {
            int tI[8], sI[8];
            float dv[8], sv[8];
#pragma unroll
            for (int r = 0; r < 8; ++r) {
                int rr = grp * 8 + r;
                int row = (rr & 3) + 8 * (rr >> 2) + 4 * h2;
                tI[r] = dsh[row];
                sI[r] = ssh[row];
            }
#pragma unroll
            for (int r = 0; r < 8; ++r) {
                dv[r] = __half2float(dstpack[(unsigned)((tI[r] << 7) + col)]);
                sv[r] = __half2float(srcpack[(unsigned)((sI[r] << 7) + col)]);
            }
            float pre[8];
#pragma unroll
            for (int r = 0; r < 8; ++r) pre[r] = acc[grp * 8 + r] + dv[r] + sv[r];
            if (w < 2) {
#pragma unroll
                for (int r = 0; r < 8; ++r) {
                    int rr = grp * 8 + r;
                    int row = (rr & 3) + 8 * (rr >> 2) + 4 * h2;
                    msgV[0][row][dcol] = sigx(pre[r]);
                }
            } else {
#pragma unroll
                for (int r = 0; r < 8; ++r) {
                    int rr = grp * 8 + r;
                    int row = (rr & 3) + 8 * (rr >> 2) + 4 * h2;
                    msgV[1][row][dcol] = spx(pre[r]);
                }
            }
        }
        __syncthreads();
        {
            int d = tid & 63;
            int base = (tid >> 6) * 8;
#pragma unroll
            for (int j = 0; j < 8; ++j) {
                int row = base + j;
                float m = msgV[0][row][d] * msgV[1][row][d];
                unsafeAtomicAdd(&agg[(unsigned)((dsh[row] << 6) + d)], m);
            }
        }
        __syncthreads();
    }
}

// Fused final update + sorted-batch pool: val = softplus(h+agg), run-length
// accumulate, one atomic per graph transition. agg left dirty (re-memset next call).
__global__ __launch_bounds__(256) void k_pool_s(
    const float* __restrict__ h, const float* __restrict__ agg,
    const int* __restrict__ batch,
    float* __restrict__ pooled, float* __restrict__ counts) {
    int tid = threadIdx.x;
    int d = tid & 63;
    int strm = tid >> 6;
    int base = blockIdx.x * 256 + strm * 64;
    if (base >= N_NODES) return;
    int end = min(base + 64, N_NODES);
    float accum = 0.0f;
    int cnt = 0;
    int cur = batch[base];
    for (int n = base; n < end; ++n) {
        int g = batch[n];
        if (g != cur) {
            unsafeAtomicAdd(&pooled[cur * DIM + d], accum);
            if (d == 0) unsafeAtomicAdd(&counts[cur], (float)cnt);
            accum = 0.0f;
            cnt = 0;
            cur = g;
        }
        accum += softplus_f(h[(size_t)n * DIM + d] + agg[(size_t)n * DIM + d]);
        cnt++;
    }
    unsafeAtomicAdd(&pooled[cur * DIM + d], accum);
    if (d == 0) unsafeAtomicAdd(&counts[cur], (float)cnt);
}

__global__ __launch_bounds__(64) void k_mlp(
    const float* __restrict__ pooled, const float* __restrict__ counts,
    const float* __restrict__ W1, const float* __restrict__ b1,
    const float* __restrict__ W2, const float* __restrict__ b2,
    const float* __restrict__ Wo, const float* __restrict__ bo,
    float* __restrict__ out) {
    __shared__ float ps[64];
    __shared__ float h1[128];
    int g = blockIdx.x, lane = threadIdx.x;
    float cnt = fmaxf(counts[g], 1.0f);
    ps[lane] = pooled[g * DIM + lane] / cnt;
    __syncthreads();
#pragma unroll
    for (int rep = 0; rep < 2; ++rep) {
        int j = lane + rep * 64;
        float acc = b1[j];
        for (int k = 0; k < 64; ++k) acc += ps[k] * W1[k * HDIM + j];
        h1[j] = fmaxf(acc, 0.0f);
    }
    __syncthreads();
    float acc = b2[lane];
    for (int k = 0; k < 128; ++k) acc += h1[k] * W2[k * 64 + lane];
    float v = fmaxf(acc, 0.0f) * Wo[lane];
#pragma unroll
    for (int off = 32; off; off >>= 1) v += __shfl_down(v, off);
    if (lane == 0) out[g] = v + bo[0];
}

extern "C" void kernel_launch(void* const* d_in, const int* in_sizes, int n_in,
                              void* d_out, int out_size, void* d_ws, size_t ws_size,
                              hipStream_t stream) {
    const int* x = (const int*)d_in[0];
    const int* eidx = (const int*)d_in[1];
    const float* eattr = (const float*)d_in[2];
    const int* batch = (const int*)d_in[3];
    const float* emb = (const float*)d_in[4];
    const float* Wf = (const float*)d_in[5];
    const float* bf = (const float*)d_in[6];
    const float* Ws = (const float*)d_in[7];
    const float* bs = (const float*)d_in[8];
    const float* W1 = (const float*)d_in[9];
    const float* b1 = (const float*)d_in[10];
    const float* W2 = (const float*)d_in[11];
    const float* b2 = (const float*)d_in[12];
    const float* Wo = (const float*)d_in[13];
    const float* bo = (const float*)d_in[14];
    float* out = (float*)d_out;

    char* p = (char*)d_ws;
    float* h = (float*)p;        p += (size_t)N_NODES * DIM * 4;
    __half* dstpack = (__half*)p; p += (size_t)N_NODES * 2 * DIM * 2;
    __half* srcpack = (__half*)p; p += (size_t)N_NODES * 2 * DIM * 2;
    float* agg = (float*)p;      p += (size_t)N_NODES * DIM * 4;
    float* pooled = (float*)p;   p += (size_t)N_GRAPHS * DIM * 4;
    float* counts = (float*)p;   p += (size_t)N_GRAPHS * 4;
    f16* wcat = (f16*)p;         p += (size_t)NLAYER * 64 * 128 * 2;
    f16* wnode = (f16*)p;        p += (size_t)NLAYER * 256 * 64 * 2;
    f16* eattrP = (f16*)p;       p += (size_t)NTILES * 4 * 64 * 8 * 2;  // 102.4 MB
    int* hist = (int*)p;         p += (size_t)N_NODES * 4;
    int* scanbuf = (int*)p;      p += (size_t)N_NODES * 4;
    int* blocksums = (int*)p;    p += 256 * 4;
    int* cursor = (int*)p;       p += (size_t)N_NODES * 4;
    int* perm = (int*)p;         p += (size_t)N_EDGES * 4;
    int* permSrc = (int*)p;      p += (size_t)N_EDGES * 4;
    int* permDst = (int*)p;      p += (size_t)N_EDGES * 4;
    size_t used_sorted = (size_t)(p - (char*)d_ws);

    bool sorted = used_sorted <= ws_size;

    const int SCAN_BLOCKS = (N_NODES + 255) / 256;  // 196
    const int NODEMM_BLOCKS = (N_NODES + 63) / 64;  // 782

    k_wprep<<<(32768 + 65536) / 256, 256, 0, stream>>>(Wf, Ws, wcat, wnode);
    if (sorted) {
        hipMemsetAsync(hist, 0, (size_t)N_NODES * 4, stream);
        k_hist<<<N_EDGES / 256, 256, 0, stream>>>(eidx, hist);
        k_scan1<<<SCAN_BLOCKS, 256, 0, stream>>>(hist, scanbuf, blocksums);
        k_scan2<<<1, 256, 0, stream>>>(blocksums, SCAN_BLOCKS);
        k_scan3<<<SCAN_BLOCKS, 256, 0, stream>>>(scanbuf, hist, blocksums, cursor);
        k_scatter<<<N_EDGES / 256, 256, 0, stream>>>(eidx, cursor, perm, permSrc, permDst);
        k_eprep2<<<NTILES * 64 / 256, 256, 0, stream>>>(eattr, perm, eattrP);
    }
    // zero agg + pooled + counts in one shot (contiguous in the layout above)
    hipMemsetAsync(agg, 0,
                   (size_t)N_NODES * DIM * 4 + (size_t)N_GRAPHS * DIM * 4 + N_GRAPHS * 4,
                   stream);
    for (int l = 0; l < NLAYER; ++l) {
        const f16* wnl = wnode + (size_t)l * 256 * 64;
        if (l == 0) {
            k_nodemm<2><<<NODEMM_BLOCKS, 256, 0, stream>>>(
                nullptr, h, nullptr, x, emb, bf + l * DIM, bs + l * DIM, wnl,
                dstpack, srcpack);
        } else {
            k_nodemm<1><<<NODEMM_BLOCKS, 256, 0, stream>>>(
                h, h, agg, nullptr, nullptr, bf + l * DIM, bs + l * DIM, wnl,
                dstpack, srcpack);
        }
        if (sorted) {
            k_edge_s<<<2048, 256, 0, stream>>>(permSrc, permDst, eattrP, dstpack, srcpack,
                                               wcat + (size_t)l * 64 * 128, agg);
        } else {
            k_edge_u<<<2048, 256, 0, stream>>>(eidx, eattr, dstpack, srcpack,
                                               wcat + (size_t)l * 64 * 128, agg);
        }
    }
    k_pool_s<<<(N_NODES + 255) / 256, 256, 0, stream>>>(h, agg, batch, pooled, counts);
    k_mlp<<<N_GRAPHS, 64, 0, stream>>>(pooled, counts, W1, b1, W2, b2, Wo, bo, out);
}